// Round 6
// baseline (152.222 us; speedup 1.0000x reference)
//
#include <hip/hip_runtime.h>
#include <hip/hip_bf16.h>

#define ALPHA  0.2f
#define L2E    1.4426950408889634f

typedef __attribute__((ext_vector_type(8))) short  short8;
typedef __attribute__((ext_vector_type(4))) float  f32x4;
typedef unsigned short u16;

__device__ __forceinline__ u16 f2bf(float f) {
    union { float f; unsigned int u; } v; v.f = f;
    unsigned int r = (v.u + 0x7FFFu + ((v.u >> 16) & 1u)) >> 16;   // RNE
    return (u16)r;
}
__device__ __forceinline__ float lrelu(float x) { return fmaxf(x, ALPHA * x); }

// ---------------- prep: W -> wbt (bf16, [c][k]); w1 = W@a1, w2 = W@a2 ------
__global__ void prep(const float* __restrict__ W, const float* __restrict__ a1,
                     const float* __restrict__ a2, u16* __restrict__ wbt,
                     float* __restrict__ w1, float* __restrict__ w2) {
    int b = blockIdx.x;
    if (b < 64) {
        int t  = threadIdx.x;
        int kk = t >> 6;
        int c4 = (t & 63) * 4;
        int k  = b * 4 + kk;
        float4 w = *(const float4*)(W + (size_t)k * 256 + c4);
        wbt[(c4 + 0) * 256 + k] = f2bf(w.x);
        wbt[(c4 + 1) * 256 + k] = f2bf(w.y);
        wbt[(c4 + 2) * 256 + k] = f2bf(w.z);
        wbt[(c4 + 3) * 256 + k] = f2bf(w.w);
    } else {
        int bb = b - 64;                       // 0..3
        int wv = threadIdx.x >> 6, lane = threadIdx.x & 63;
        for (int kk = 0; kk < 16; ++kk) {
            int k = bb * 64 + wv * 16 + kk;
            float4 wv4 = *(const float4*)(W + (size_t)k * 256 + 4 * lane);
            float4 a14 = *(const float4*)(a1 + 4 * lane);
            float4 a24 = *(const float4*)(a2 + 4 * lane);
            float d1 = wv4.x*a14.x + wv4.y*a14.y + wv4.z*a14.z + wv4.w*a14.w;
            float d2 = wv4.x*a24.x + wv4.y*a24.y + wv4.z*a24.z + wv4.w*a24.w;
            #pragma unroll
            for (int off = 32; off; off >>= 1) {
                d1 += __shfl_xor(d1, off);
                d2 += __shfl_xor(d2, off);
            }
            if (lane == 0) { w1[k] = d1; w2[k] = d2; }
        }
    }
}

// ---------------- prep2: gw1=gamma*w1, gw2=gamma*w2, scal={sgw1,sgw2,bw1,bw2}
__global__ void prep2(const float* __restrict__ gamma, const float* __restrict__ beta,
                      const float* __restrict__ w1, const float* __restrict__ w2,
                      float* __restrict__ gw1, float* __restrict__ gw2,
                      float* __restrict__ scal) {
    int t = threadIdx.x;                        // 256 threads
    float w1v = w1[t], w2v = w2[t], g = gamma[t], bt = beta[t];
    float v0 = g * w1v, v1 = g * w2v;
    gw1[t] = v0; gw2[t] = v1;
    float v2 = bt * w1v, v3 = bt * w2v;
    #pragma unroll
    for (int off = 32; off; off >>= 1) {
        v0 += __shfl_xor(v0, off); v1 += __shfl_xor(v1, off);
        v2 += __shfl_xor(v2, off); v3 += __shfl_xor(v3, off);
    }
    __shared__ float red[4][4];
    int wv = t >> 6, lane = t & 63;
    if (lane == 0) { red[wv][0] = v0; red[wv][1] = v1; red[wv][2] = v2; red[wv][3] = v3; }
    __syncthreads();
    if (t == 0) {
        scal[0] = red[0][0] + red[1][0] + red[2][0] + red[3][0];
        scal[1] = red[0][1] + red[1][1] + red[2][1] + red[3][1];
        scal[2] = red[0][2] + red[1][2] + red[2][2] + red[3][2];
        scal[3] = red[0][3] + red[1][3] + red[2][3] + red[3][3];
    }
}

// ======================= K1: gather + LN + s1/s2 ===========================
// grid 2048 x 256 thr. No LDS, no barriers. Wave-per-row, 8 rows/wave.
// xg element (R, c) stored at R*256 + (((c>>3)^(R&7))<<3) + (c&7)  (swizzle baked)
__global__ __launch_bounds__(256, 4)
void k1(const int* __restrict__ item_seq, const float* __restrict__ emb,
        const float* __restrict__ pos, const float* __restrict__ gamma,
        const float* __restrict__ beta, const float* __restrict__ gw1,
        const float* __restrict__ gw2, const float* __restrict__ scal,
        float* __restrict__ s1g, float* __restrict__ s2g, u16* __restrict__ xg)
{
    const int tid = threadIdx.x, lane = tid & 63, wv = tid >> 6;
    float4 g4 = *(const float4*)(gamma + 4 * lane);
    float4 b4 = *(const float4*)(beta  + 4 * lane);
    float4 u4 = *(const float4*)(gw1   + 4 * lane);
    float4 t4 = *(const float4*)(gw2   + 4 * lane);
    float4 sc = *(const float4*)scal;           // sgw1, sgw2, bw1, bw2
    const int Rbase = blockIdx.x * 32 + wv * 8;
    #pragma unroll 2
    for (int it = 0; it < 8; ++it) {
        int R = Rbase + it;
        int r = R & 255;
        int iw = item_seq[R];
        float4 e = *(const float4*)(emb + (size_t)iw * 256 + 4 * lane);
        float4 p = *(const float4*)(pos + (size_t)r  * 256 + 4 * lane);
        float4 v; v.x = e.x + p.x; v.y = e.y + p.y; v.z = e.z + p.z; v.w = e.w + p.w;
        float s  = v.x + v.y + v.z + v.w;
        float q  = v.x*v.x + v.y*v.y + v.z*v.z + v.w*v.w;
        float d1 = v.x*u4.x + v.y*u4.y + v.z*u4.z + v.w*u4.w;
        float d2 = v.x*t4.x + v.y*t4.y + v.z*t4.z + v.w*t4.w;
        #pragma unroll
        for (int off = 32; off; off >>= 1) {    // one chain, ILP-4
            s  += __shfl_xor(s,  off);
            q  += __shfl_xor(q,  off);
            d1 += __shfl_xor(d1, off);
            d2 += __shfl_xor(d2, off);
        }
        float mu  = s * (1.0f / 256.0f);
        float var = q * (1.0f / 256.0f) - mu * mu;
        float rs  = rsqrtf(var + 1e-12f);
        if (lane == 0) {
            s1g[R] = rs * (d1 - mu * sc.x) + sc.z;
            s2g[R] = rs * (d2 - mu * sc.y) + sc.w;
        }
        float y0 = (v.x - mu) * rs * g4.x + b4.x;
        float y1 = (v.y - mu) * rs * g4.y + b4.y;
        float y2 = (v.z - mu) * rs * g4.z + b4.z;
        float y3 = (v.w - mu) * rs * g4.w + b4.w;
        ushort4 o; o.x = f2bf(y0); o.y = f2bf(y1); o.z = f2bf(y2); o.w = f2bf(y3);
        *(ushort4*)&xg[(size_t)R * 256 + ((((lane >> 1) ^ (R & 7))) << 3) + (lane & 1) * 4] = o;
    }
}

// ======================= K2: GEMM1 h = x @ W, write hT =====================
// grid 1024 (64 rows each) x 256 thr. LDS 32KB -> 4 blocks/CU at 128 VGPR.
// htg element (b, c, j): b*65536 + c*256 + ((j>>6)^((c>>3)&3))*64
//                        + (((j>>3)&7)^(c&7))*8 + (j&7)
__global__ __launch_bounds__(256, 4)
void k2(const u16* __restrict__ xg, const u16* __restrict__ wbt,
        u16* __restrict__ htg)
{
    __shared__ u16 xs[64 * 256];   // 32 KB; x-tile then hT-stage [c 256][islot 64]
    const int blk = blockIdx.x;
    const int b = blk >> 2, iq = blk & 3;
    const int R0 = blk * 64;
    const int tid = threadIdx.x;
    const int lane = tid & 63, wv = tid >> 6, g = lane >> 4, li = lane & 15;

    // stage x rows R0..R0+63 (linear 32KB; swizzle already baked in xg)
    #pragma unroll
    for (int rr = 0; rr < 8; ++rr) {
        const u16* src = xg + (size_t)R0 * 256 + rr * 2048 + wv * 512 + lane * 8;
        u16* dst = &xs[rr * 2048 + wv * 512];
        __builtin_amdgcn_global_load_lds(
            (const __attribute__((address_space(1))) void*)src,
            (__attribute__((address_space(3))) void*)dst, 16, 0, 0);
    }
    __syncthreads();

    // wave = 16 rows x 256 cols; acc 64 VGPRs
    f32x4 acc[16];
    #pragma unroll
    for (int t = 0; t < 16; ++t) acc[t] = (f32x4){0.f, 0.f, 0.f, 0.f};

    const int rl = wv * 16 + li;
    #pragma unroll
    for (int ks = 0; ks < 8; ++ks) {
        short8 af = *(const short8*)&xs[rl * 256 + (((ks * 4 + g) ^ (rl & 7)) << 3)];
        #pragma unroll
        for (int nh = 0; nh < 2; ++nh)
            #pragma unroll
            for (int q = 0; q < 2; ++q) {
                short8 bfr[4];
                #pragma unroll
                for (int nt = 0; nt < 4; ++nt) {
                    int c = nh * 128 + q * 64 + nt * 16 + li;
                    bfr[nt] = *(const short8*)(wbt + (size_t)c * 256 + ks * 32 + g * 8);
                }
                #pragma unroll
                for (int nt = 0; nt < 4; ++nt)
                    acc[nh * 8 + q * 4 + nt] = __builtin_amdgcn_mfma_f32_16x16x32_bf16(
                        af, bfr[nt], acc[nh * 8 + q * 4 + nt], 0, 0, 0);
            }
    }
    __syncthreads();   // all xs (=x) reads done

    // transpose into hT-stage [c 256][islot 64] (i-slot swizzle ^ (c&7))
    {
        int ichunk = (wv << 1) | (g >> 1);      // (wv*16+4g)>>3
        int isub   = (g & 1) * 4;
        #pragma unroll
        for (int nh = 0; nh < 2; ++nh)
            #pragma unroll
            for (int nt = 0; nt < 8; ++nt) {
                int c = nh * 128 + nt * 16 + li;
                f32x4 a = acc[nh * 8 + nt];
                uint2 v;
                v.x = (unsigned)f2bf(a[0]) | ((unsigned)f2bf(a[1]) << 16);
                v.y = (unsigned)f2bf(a[2]) | ((unsigned)f2bf(a[3]) << 16);
                *(uint2*)&xs[c * 64 + ((ichunk ^ (c & 7)) << 3) + isub] = v;
            }
    }
    __syncthreads();

    // copy out: thread = c row (128B), quarter swizzled by (c>>3)&3
    {
        const uint4* sp = (const uint4*)&xs[tid * 64];
        uint4* dp = (uint4*)(htg + (size_t)b * 65536 + tid * 256
                             + ((iq ^ ((tid >> 3) & 3)) << 6));
        #pragma unroll
        for (int k = 0; k < 8; ++k) dp[k] = sp[k];
    }
}

// ======================= K3: softmax + PV ==================================
// grid 1024: block = (b, c-quarter). LDS ~36KB -> 4 blocks/CU at 128 VGPR.
__global__ __launch_bounds__(256, 4)
void k3(const float* __restrict__ s1g, const float* __restrict__ s2g,
        const u16* __restrict__ htg, float* __restrict__ out)
{
    __shared__ u16 hts[64 * 256];            // 32 KB: [cl 64][j-image 256]
    __shared__ __align__(16) float s2s[256], s1S[256], mS[256], lS[256];
    __shared__ float red[4];
    const int bid = blockIdx.x;
    const int b   = bid >> 2, cq = bid & 3;
    const int tid = threadIdx.x;
    const int lane = tid & 63, wv = tid >> 6, g = lane >> 4, li = lane & 15;

    // issue hT staging first (32KB linear); latency hides under stats
    #pragma unroll
    for (int rr = 0; rr < 8; ++rr) {
        const u16* src = htg + (size_t)b * 65536 + cq * 16384
                         + rr * 2048 + wv * 512 + lane * 8;
        u16* dst = &hts[rr * 2048 + wv * 512];
        __builtin_amdgcn_global_load_lds(
            (const __attribute__((address_space(1))) void*)src,
            (__attribute__((address_space(3))) void*)dst, 16, 0, 0);
    }

    // stats
    float s1v = s1g[b * 256 + tid];
    float s2v = s2g[b * 256 + tid];
    s2s[tid] = s2v; s1S[tid] = s1v;
    float m = s2v;
    #pragma unroll
    for (int off = 32; off; off >>= 1) m = fmaxf(m, __shfl_xor(m, off));
    if (lane == 0) red[wv] = m;
    __syncthreads();
    {
        float s2max = fmaxf(fmaxf(red[0], red[1]), fmaxf(red[2], red[3]));
        float mi  = lrelu(s1v + s2max);
        float sum = 0.f;
        const float4* s2v4 = (const float4*)s2s;
        #pragma unroll 8
        for (int j4 = 0; j4 < 64; ++j4) {
            float4 sv = s2v4[j4];
            sum += __builtin_amdgcn_exp2f((lrelu(s1v + sv.x) - mi) * L2E);
            sum += __builtin_amdgcn_exp2f((lrelu(s1v + sv.y) - mi) * L2E);
            sum += __builtin_amdgcn_exp2f((lrelu(s1v + sv.z) - mi) * L2E);
            sum += __builtin_amdgcn_exp2f((lrelu(s1v + sv.w) - mi) * L2E);
        }
        mS[tid] = mi; lS[tid] = 1.0f / sum;
    }
    __syncthreads();   // drains staging + publishes mS/lS

    // PV: out[i 256][c 64] = P @ h ; wave = i 64-range
    f32x4 oacc[4][4];
    #pragma unroll
    for (int mt = 0; mt < 4; ++mt)
        #pragma unroll
        for (int nt = 0; nt < 4; ++nt)
            oacc[mt][nt] = (f32x4){0.f, 0.f, 0.f, 0.f};

    float s1r[4], mv[4], lv[4];
    #pragma unroll
    for (int mt = 0; mt < 4; ++mt) {
        int i = wv * 64 + mt * 16 + li;
        s1r[mt] = s1S[i]; mv[mt] = mS[i]; lv[mt] = lS[i];
    }

    #pragma unroll
    for (int js = 0; js < 8; ++js) {
        float s2l[8];
        #pragma unroll
        for (int jj = 0; jj < 8; ++jj) s2l[jj] = s2s[js * 32 + g * 8 + jj];

        short8 pfr[4];
        #pragma unroll
        for (int mt = 0; mt < 4; ++mt) {
            union { unsigned int u[4]; short8 s; } pk;
            #pragma unroll
            for (int q2 = 0; q2 < 4; ++q2) {
                float e0 = lrelu(s1r[mt] + s2l[2 * q2]);
                float e1 = lrelu(s1r[mt] + s2l[2 * q2 + 1]);
                float p0 = __builtin_amdgcn_exp2f((e0 - mv[mt]) * L2E) * lv[mt];
                float p1 = __builtin_amdgcn_exp2f((e1 - mv[mt]) * L2E) * lv[mt];
                pk.u[q2] = (unsigned int)f2bf(p0) | ((unsigned int)f2bf(p1) << 16);
            }
            pfr[mt] = pk.s;
        }
        int jb = js * 4 + g;                   // j-chunk 0..31
        #pragma unroll
        for (int nt = 0; nt < 4; ++nt) {
            int cl = nt * 16 + li;
            short8 vf = *(const short8*)&hts[cl * 256
                          + (((jb >> 3) ^ ((cl >> 3) & 3)) << 6)
                          + ((((jb & 7) ^ (cl & 7))) << 3)];
            #pragma unroll
            for (int mt = 0; mt < 4; ++mt)
                oacc[mt][nt] = __builtin_amdgcn_mfma_f32_16x16x32_bf16(
                    pfr[mt], vf, oacc[mt][nt], 0, 0, 0);
        }
    }

    size_t ob = (size_t)b * (256 * 256);
    #pragma unroll
    for (int mt = 0; mt < 4; ++mt)
        #pragma unroll
        for (int nt = 0; nt < 4; ++nt) {
            int c  = cq * 64 + nt * 16 + li;
            int i0 = wv * 64 + mt * 16 + 4 * g;
            #pragma unroll
            for (int q2 = 0; q2 < 4; ++q2)
                out[ob + (size_t)(i0 + q2) * 256 + c] = oacc[mt][nt][q2];
        }
}

extern "C" void kernel_launch(void* const* d_in, const int* in_sizes, int n_in,
                              void* d_out, int out_size, void* d_ws, size_t ws_size,
                              hipStream_t stream) {
    (void)in_sizes; (void)n_in; (void)out_size; (void)ws_size;
    const int*   seq   = (const int*)d_in[0];
    const float* emb   = (const float*)d_in[1];
    const float* pos   = (const float*)d_in[2];
    const float* W     = (const float*)d_in[3];
    const float* a1    = (const float*)d_in[4];
    const float* a2    = (const float*)d_in[5];
    const float* gamma = (const float*)d_in[6];
    const float* beta  = (const float*)d_in[7];

    char* ws = (char*)d_ws;
    u16*   wbt  = (u16*)ws;                      // 128 KB
    float* w1   = (float*)(ws + 131072);         // 1 KB
    float* w2   = (float*)(ws + 132096);         // 1 KB
    float* gw1f = (float*)(ws + 133120);         // 1 KB
    float* gw2f = (float*)(ws + 134144);         // 1 KB
    float* scal = (float*)(ws + 135168);         // 1 KB pad
    float* s1g  = (float*)(ws + 136192);         // 256 KB
    float* s2g  = (float*)(ws + 398336);         // 256 KB
    u16*   htg  = (u16*)(ws + 660480);           // 32 MB

    // x (bf16, swizzled) lives in the first 32MB of d_out; K3 overwrites all
    // of d_out afterwards (strict stream order K1 -> K2 -> K3).
    u16* xg = (u16*)d_out;

    hipLaunchKernelGGL(prep,  dim3(68), dim3(256), 0, stream, W, a1, a2, wbt, w1, w2);
    hipLaunchKernelGGL(prep2, dim3(1),  dim3(256), 0, stream, gamma, beta, w1, w2, gw1f, gw2f, scal);
    hipLaunchKernelGGL(k1, dim3(2048), dim3(256), 0, stream,
                       seq, emb, pos, gamma, beta, gw1f, gw2f, scal, s1g, s2g, xg);
    hipLaunchKernelGGL(k2, dim3(1024), dim3(256), 0, stream, xg, wbt, htg);
    hipLaunchKernelGGL(k3, dim3(1024), dim3(256), 0, stream,
                       s1g, s2g, htg, (float*)d_out);
}

// Round 7
// 149.864 us; speedup vs baseline: 1.0157x; 1.0157x over previous
//
#include <hip/hip_runtime.h>
#include <hip/hip_bf16.h>

#define ALPHA  0.2f
#define L2E    1.4426950408889634f

typedef __attribute__((ext_vector_type(8))) short  short8;
typedef __attribute__((ext_vector_type(4))) float  f32x4;
typedef unsigned short u16;

__device__ __forceinline__ u16 f2bf(float f) {
    union { float f; unsigned int u; } v; v.f = f;
    unsigned int r = (v.u + 0x7FFFu + ((v.u >> 16) & 1u)) >> 16;   // RNE
    return (u16)r;
}
__device__ __forceinline__ float lrelu(float x) { return fmaxf(x, ALPHA * x); }
__device__ __forceinline__ unsigned pk2(float a, float b) {
    return (unsigned)f2bf(a) | ((unsigned)f2bf(b) << 16);
}

#define GLD16(src, dst) __builtin_amdgcn_global_load_lds( \
    (const __attribute__((address_space(1))) void*)(src), \
    (__attribute__((address_space(3))) void*)(dst), 16, 0, 0)

// ---- prep: W -> wbtc [ks 8][c 256][36 pad] (bf16, k-chunk-major, padded rows);
//      w1 = W@a1, w2 = W@a2
__global__ void prep(const float* __restrict__ W, const float* __restrict__ a1,
                     const float* __restrict__ a2, u16* __restrict__ wbtc,
                     float* __restrict__ w1, float* __restrict__ w2) {
    int b = blockIdx.x;
    if (b < 64) {
        int t  = threadIdx.x;
        int kk = t >> 6;                       // 0..3
        int c4 = (t & 63) * 4;
        int k  = b * 4 + kk;
        float4 w = *(const float4*)(W + (size_t)k * 256 + c4);
        size_t base = (size_t)(k >> 5) * 9216 + (k & 31);
        wbtc[base + (size_t)(c4 + 0) * 36] = f2bf(w.x);
        wbtc[base + (size_t)(c4 + 1) * 36] = f2bf(w.y);
        wbtc[base + (size_t)(c4 + 2) * 36] = f2bf(w.z);
        wbtc[base + (size_t)(c4 + 3) * 36] = f2bf(w.w);
    } else {
        int bb = b - 64;                       // 0..3
        int wv = threadIdx.x >> 6, lane = threadIdx.x & 63;
        for (int kk = 0; kk < 16; ++kk) {
            int k = bb * 64 + wv * 16 + kk;
            float4 wv4 = *(const float4*)(W + (size_t)k * 256 + 4 * lane);
            float4 a14 = *(const float4*)(a1 + 4 * lane);
            float4 a24 = *(const float4*)(a2 + 4 * lane);
            float d1 = wv4.x*a14.x + wv4.y*a14.y + wv4.z*a14.z + wv4.w*a14.w;
            float d2 = wv4.x*a24.x + wv4.y*a24.y + wv4.z*a24.z + wv4.w*a24.w;
            #pragma unroll
            for (int off = 32; off; off >>= 1) {
                d1 += __shfl_xor(d1, off);
                d2 += __shfl_xor(d2, off);
            }
            if (lane == 0) { w1[k] = d1; w2[k] = d2; }
        }
    }
}

// ======================= K1: gather + LN + s1/s2 ===========================
// grid 2048 x 256. No LDS/barriers. Wave-per-row, 8 rows batched for MLP.
// xg element (R,c) at R*256 + (((c>>3)^(R&7))<<3) + (c&7)   (bank-swizzle baked)
__global__ __launch_bounds__(256, 3)
void k1(const int* __restrict__ item_seq, const float* __restrict__ emb,
        const float* __restrict__ pos, const float* __restrict__ gamma,
        const float* __restrict__ beta, const float* __restrict__ w1,
        const float* __restrict__ w2,
        float* __restrict__ s1g, float* __restrict__ s2g, u16* __restrict__ xg)
{
    const int tid = threadIdx.x, lane = tid & 63, wv = tid >> 6;
    float4 g4  = *(const float4*)(gamma + 4 * lane);
    float4 b4  = *(const float4*)(beta  + 4 * lane);
    float4 w14 = *(const float4*)(w1    + 4 * lane);
    float4 w24 = *(const float4*)(w2    + 4 * lane);
    float4 u4, t4;
    u4.x = g4.x*w14.x; u4.y = g4.y*w14.y; u4.z = g4.z*w14.z; u4.w = g4.w*w14.w;
    t4.x = g4.x*w24.x; t4.y = g4.y*w24.y; t4.z = g4.z*w24.z; t4.w = g4.w*w24.w;
    // scalars: sgw1, sgw2, bw1, bw2 (wave-wide reduce, once)
    float sA = u4.x + u4.y + u4.z + u4.w;
    float sB = t4.x + t4.y + t4.z + t4.w;
    float sC = b4.x*w14.x + b4.y*w14.y + b4.z*w14.z + b4.w*w14.w;
    float sD = b4.x*w24.x + b4.y*w24.y + b4.z*w24.z + b4.w*w24.w;
    #pragma unroll
    for (int off = 32; off; off >>= 1) {
        sA += __shfl_xor(sA, off); sB += __shfl_xor(sB, off);
        sC += __shfl_xor(sC, off); sD += __shfl_xor(sD, off);
    }

    const int Rbase = blockIdx.x * 32 + wv * 8;
    int iw[8];
    #pragma unroll
    for (int it = 0; it < 8; ++it) iw[it] = item_seq[Rbase + it];
    float4 e[8], p[8];
    #pragma unroll
    for (int it = 0; it < 8; ++it)
        e[it] = *(const float4*)(emb + (size_t)iw[it] * 256 + 4 * lane);
    #pragma unroll
    for (int it = 0; it < 8; ++it)
        p[it] = *(const float4*)(pos + (size_t)((Rbase + it) & 255) * 256 + 4 * lane);

    float4 v[8]; float s[8], q[8], d1[8], d2[8];
    #pragma unroll
    for (int it = 0; it < 8; ++it) {
        float4 vv;
        vv.x = e[it].x + p[it].x; vv.y = e[it].y + p[it].y;
        vv.z = e[it].z + p[it].z; vv.w = e[it].w + p[it].w;
        v[it] = vv;
        s[it]  = vv.x + vv.y + vv.z + vv.w;
        q[it]  = vv.x*vv.x + vv.y*vv.y + vv.z*vv.z + vv.w*vv.w;
        d1[it] = vv.x*u4.x + vv.y*u4.y + vv.z*u4.z + vv.w*u4.w;
        d2[it] = vv.x*t4.x + vv.y*t4.y + vv.z*t4.z + vv.w*t4.w;
    }
    #pragma unroll
    for (int off = 32; off; off >>= 1) {      // one chain, ILP-32
        #pragma unroll
        for (int it = 0; it < 8; ++it) {
            s[it]  += __shfl_xor(s[it],  off);
            q[it]  += __shfl_xor(q[it],  off);
            d1[it] += __shfl_xor(d1[it], off);
            d2[it] += __shfl_xor(d2[it], off);
        }
    }
    #pragma unroll
    for (int it = 0; it < 8; ++it) {
        int R = Rbase + it;
        float mu  = s[it] * (1.0f / 256.0f);
        float var = q[it] * (1.0f / 256.0f) - mu * mu;
        float rs  = rsqrtf(var + 1e-12f);
        if (lane == 0) {
            s1g[R] = rs * (d1[it] - mu * sA) + sC;
            s2g[R] = rs * (d2[it] - mu * sB) + sD;
        }
        float y0 = (v[it].x - mu) * rs * g4.x + b4.x;
        float y1 = (v[it].y - mu) * rs * g4.y + b4.y;
        float y2 = (v[it].z - mu) * rs * g4.z + b4.z;
        float y3 = (v[it].w - mu) * rs * g4.w + b4.w;
        ushort4 o; o.x = f2bf(y0); o.y = f2bf(y1); o.z = f2bf(y2); o.w = f2bf(y3);
        *(ushort4*)&xg[(size_t)R * 256 + ((((lane >> 1) ^ (R & 7))) << 3)
                       + (lane & 1) * 4] = o;
    }
}

// ======================= K2: GEMM1 h = x @ W, write hT =====================
// grid 1024 (64 rows each) x 256 thr. LDS 68KB -> 2 blocks/CU.
// htg image: [b][c 256][unit 32]: element (c, jg) at unit (jg>>3)^(c&7), byte (jg&7)*2
__global__ __launch_bounds__(256, 2)
void k2(const u16* __restrict__ xg, const u16* __restrict__ wbtc,
        u16* __restrict__ htg)
{
    __shared__ u16 xs[16384];      // 32KB: x-tile [64 r][256 k]; later hT [256 c][64 jl]
    __shared__ u16 wc[2][9216];    // 18KB x2: W chunk [c 256][36]
    const int blk = blockIdx.x;
    const int b = blk >> 2, jq = blk & 3;
    const int R0 = blk * 64;
    const int tid = threadIdx.x;
    const int lane = tid & 63, wv = tid >> 6, g = lane >> 4, li = lane & 15;

    // stage x: 32KB linear (swizzle baked in xg)
    #pragma unroll
    for (int it = 0; it < 8; ++it) {
        int sb = (it * 4 + wv) * 64;
        GLD16(xg + (size_t)R0 * 256 + (size_t)(sb + lane) * 8, &xs[sb * 8]);
    }
    // stage W chunk 0: 18KB linear
    #pragma unroll
    for (int it = 0; it < 5; ++it) {
        int w = it * 4 + wv;
        if (w < 18) GLD16(wbtc + (size_t)(w * 64 + lane) * 8, &wc[0][w * 512]);
    }
    __syncthreads();

    f32x4 acc[16];
    #pragma unroll
    for (int t = 0; t < 16; ++t) acc[t] = (f32x4){0.f, 0.f, 0.f, 0.f};

    const int rl = wv * 16 + li;
    for (int ks = 0; ks < 8; ++ks) {
        if (ks < 7) {
            #pragma unroll
            for (int it = 0; it < 5; ++it) {
                int w = it * 4 + wv;
                if (w < 18)
                    GLD16(wbtc + (size_t)(ks + 1) * 9216 + (size_t)(w * 64 + lane) * 8,
                          &wc[(ks + 1) & 1][w * 512]);
            }
        }
        const u16* wcur = wc[ks & 1];
        short8 af = *(const short8*)&xs[rl * 256 + (((ks * 4 + g) ^ (rl & 7)) << 3)];
        #pragma unroll
        for (int nt = 0; nt < 16; ++nt) {
            short8 bf = *(const short8*)&wcur[(nt * 16 + li) * 36 + g * 8];
            acc[nt] = __builtin_amdgcn_mfma_f32_16x16x32_bf16(af, bf, acc[nt], 0, 0, 0);
        }
        __syncthreads();   // chunk ks+1 visible; wc[ks&1] free for ks+2 staging
    }

    // pack hT into xs: [c 256][jl 64], unit slot = (jl>>3)^(c&7)
    #pragma unroll
    for (int nt = 0; nt < 16; ++nt) {
        int c  = nt * 16 + li;
        int jl = wv * 16 + 4 * g;
        uint2 o; o.x = pk2(acc[nt][0], acc[nt][1]); o.y = pk2(acc[nt][2], acc[nt][3]);
        *(uint2*)&xs[c * 64 + ((((jl >> 3) ^ (c & 7))) << 3) + (jl & 7)] = o;
    }
    __syncthreads();

    // store: wave -> 64 c-rows; per instr 8 c x 128B segments (contiguous)
    #pragma unroll
    for (int i8 = 0; i8 < 8; ++i8) {
        int c = wv * 64 + i8 * 8 + (lane >> 3);
        int u = lane & 7;
        *(uint4*)(htg + (size_t)b * 65536 + (size_t)c * 256 + jq * 64 + u * 8) =
            *(const uint4*)&xs[c * 64 + u * 8];
    }
}

// ======================= K3: softmax + PV ==================================
// grid 1024: block = (b, c-quarter). LDS ~36KB -> 4 blocks/CU.
__global__ __launch_bounds__(256, 4)
void k3(const float* __restrict__ s1g, const float* __restrict__ s2g,
        const u16* __restrict__ htg, float* __restrict__ out)
{
    __shared__ u16 hts[16384];               // 32KB: [cl 64][j units 32], slot = jb^(cl&7)
    __shared__ __align__(16) float s2s[256], s1S[256], mS[256], lS[256];
    __shared__ float red[4];
    const int bid = blockIdx.x;
    const int b   = bid >> 2, cq = bid & 3;
    const int tid = threadIdx.x;
    const int lane = tid & 63, wv = tid >> 6, g = lane >> 4, li = lane & 15;

    // stage hT slice: 32KB contiguous
    #pragma unroll
    for (int it = 0; it < 8; ++it) {
        int sb = (it * 4 + wv) * 64;
        GLD16(htg + (size_t)b * 65536 + (size_t)cq * 16384 + (size_t)(sb + lane) * 8,
              &hts[sb * 8]);
    }

    float s1v = s1g[b * 256 + tid];
    float s2v = s2g[b * 256 + tid];
    s2s[tid] = s2v; s1S[tid] = s1v;
    float m = s2v;
    #pragma unroll
    for (int off = 32; off; off >>= 1) m = fmaxf(m, __shfl_xor(m, off));
    if (lane == 0) red[wv] = m;
    __syncthreads();
    {
        float s2max = fmaxf(fmaxf(red[0], red[1]), fmaxf(red[2], red[3]));
        float mi  = lrelu(s1v + s2max);
        float sum = 0.f;
        const float4* s2v4 = (const float4*)s2s;
        #pragma unroll 8
        for (int j4 = 0; j4 < 64; ++j4) {
            float4 sv = s2v4[j4];
            sum += __builtin_amdgcn_exp2f((lrelu(s1v + sv.x) - mi) * L2E);
            sum += __builtin_amdgcn_exp2f((lrelu(s1v + sv.y) - mi) * L2E);
            sum += __builtin_amdgcn_exp2f((lrelu(s1v + sv.z) - mi) * L2E);
            sum += __builtin_amdgcn_exp2f((lrelu(s1v + sv.w) - mi) * L2E);
        }
        mS[tid] = mi; lS[tid] = 1.0f / sum;
    }
    __syncthreads();   // drains staging + publishes stats

    f32x4 oacc[4][4];
    #pragma unroll
    for (int mt = 0; mt < 4; ++mt)
        #pragma unroll
        for (int nt = 0; nt < 4; ++nt)
            oacc[mt][nt] = (f32x4){0.f, 0.f, 0.f, 0.f};

    float s1r[4], mv[4], lv[4];
    #pragma unroll
    for (int mt = 0; mt < 4; ++mt) {
        int i = wv * 64 + mt * 16 + li;
        s1r[mt] = s1S[i]; mv[mt] = mS[i]; lv[mt] = lS[i];
    }

    #pragma unroll
    for (int js = 0; js < 8; ++js) {
        float s2l[8];
        #pragma unroll
        for (int jj = 0; jj < 8; ++jj) s2l[jj] = s2s[js * 32 + g * 8 + jj];

        short8 pfr[4];
        #pragma unroll
        for (int mt = 0; mt < 4; ++mt) {
            union { unsigned int u[4]; short8 s; } pk;
            #pragma unroll
            for (int q2 = 0; q2 < 4; ++q2) {
                float e0 = lrelu(s1r[mt] + s2l[2 * q2]);
                float e1 = lrelu(s1r[mt] + s2l[2 * q2 + 1]);
                float p0 = __builtin_amdgcn_exp2f((e0 - mv[mt]) * L2E) * lv[mt];
                float p1 = __builtin_amdgcn_exp2f((e1 - mv[mt]) * L2E) * lv[mt];
                pk.u[q2] = pk2(0.f, 0.f) * 0u | ((unsigned)f2bf(p0) | ((unsigned)f2bf(p1) << 16));
            }
            pfr[mt] = pk.s;
        }
        int jb = js * 4 + g;                   // j-chunk 0..31
        #pragma unroll
        for (int nt = 0; nt < 4; ++nt) {
            int cl = nt * 16 + li;
            short8 vf = *(const short8*)&hts[cl * 256 + ((jb ^ (cl & 7)) << 3)];
            #pragma unroll
            for (int mt = 0; mt < 4; ++mt)
                oacc[mt][nt] = __builtin_amdgcn_mfma_f32_16x16x32_bf16(
                    pfr[mt], vf, oacc[mt][nt], 0, 0, 0);
        }
    }

    size_t ob = (size_t)b * (256 * 256);
    #pragma unroll
    for (int mt = 0; mt < 4; ++mt)
        #pragma unroll
        for (int nt = 0; nt < 4; ++nt) {
            int c  = cq * 64 + nt * 16 + li;
            int i0 = wv * 64 + mt * 16 + 4 * g;
            #pragma unroll
            for (int q2 = 0; q2 < 4; ++q2)
                out[ob + (size_t)(i0 + q2) * 256 + c] = oacc[mt][nt][q2];
        }
}

extern "C" void kernel_launch(void* const* d_in, const int* in_sizes, int n_in,
                              void* d_out, int out_size, void* d_ws, size_t ws_size,
                              hipStream_t stream) {
    (void)in_sizes; (void)n_in; (void)out_size; (void)ws_size;
    const int*   seq   = (const int*)d_in[0];
    const float* emb   = (const float*)d_in[1];
    const float* pos   = (const float*)d_in[2];
    const float* W     = (const float*)d_in[3];
    const float* a1    = (const float*)d_in[4];
    const float* a2    = (const float*)d_in[5];
    const float* gamma = (const float*)d_in[6];
    const float* beta  = (const float*)d_in[7];

    char* ws = (char*)d_ws;
    u16*   wbtc = (u16*)ws;                      // 147456 B
    float* w1   = (float*)(ws + 147456);         // 1 KB
    float* w2   = (float*)(ws + 148480);         // 1 KB
    float* s1g  = (float*)(ws + 149504);         // 256 KB
    float* s2g  = (float*)(ws + 411648);         // 256 KB
    u16*   htg  = (u16*)(ws + 673792);           // 32 MB

    // x (bf16, swizzled) lives in first 32MB of d_out; k3 overwrites d_out
    // only after k2 has consumed xg (strict stream order).
    u16* xg = (u16*)d_out;

    hipLaunchKernelGGL(prep, dim3(68), dim3(256), 0, stream, W, a1, a2, wbtc, w1, w2);
    hipLaunchKernelGGL(k1, dim3(2048), dim3(256), 0, stream,
                       seq, emb, pos, gamma, beta, w1, w2, s1g, s2g, xg);
    hipLaunchKernelGGL(k2, dim3(1024), dim3(256), 0, stream, xg, wbtc, htg);
    hipLaunchKernelGGL(k3, dim3(1024), dim3(256), 0, stream,
                       s1g, s2g, htg, (float*)d_out);
}

// Round 8
// 70.770 us; speedup vs baseline: 2.1509x; 2.1176x over previous
//
#include <hip/hip_runtime.h>
#include <hip/hip_bf16.h>

#define ALPHA  0.2f
#define L2E    1.4426950408889634f

typedef __attribute__((ext_vector_type(8))) short  short8;
typedef __attribute__((ext_vector_type(4))) float  f32x4;
typedef unsigned short u16;

__device__ __forceinline__ u16 f2bf(float f) {
    union { float f; unsigned int u; } v; v.f = f;
    unsigned int r = (v.u + 0x7FFFu + ((v.u >> 16) & 1u)) >> 16;   // RNE
    return (u16)r;
}
__device__ __forceinline__ float lrelu(float x) { return fmaxf(x, ALPHA * x); }
__device__ __forceinline__ unsigned pk2(float a, float b) {
    return (unsigned)f2bf(a) | ((unsigned)f2bf(b) << 16);
}

// ---- prep: W -> wfrag[pair 128][lane 64][8] (B-fragment-contiguous bf16),
//      pair = ks*16 + cblock; lane g*16+li holds W[k=ks*32+g*8+j][c=cb*16+li].
//      Also w1 = W@a1, w2 = W@a2.
__global__ void prep(const float* __restrict__ W, const float* __restrict__ a1,
                     const float* __restrict__ a2, u16* __restrict__ wfrag,
                     float* __restrict__ w1, float* __restrict__ w2) {
    int b = blockIdx.x;
    if (b < 64) {
        int t    = threadIdx.x;
        int pair = b * 2 + (t >> 7);
        int l    = (t >> 1) & 63;
        int jh   = (t & 1) * 4;
        int ks   = pair >> 4, cb = pair & 15;
        int c  = cb * 16 + (l & 15);
        int k0 = ks * 32 + (l >> 4) * 8 + jh;
        ushort4 o;
        o.x = f2bf(W[(size_t)(k0 + 0) * 256 + c]);
        o.y = f2bf(W[(size_t)(k0 + 1) * 256 + c]);
        o.z = f2bf(W[(size_t)(k0 + 2) * 256 + c]);
        o.w = f2bf(W[(size_t)(k0 + 3) * 256 + c]);
        *(ushort4*)&wfrag[(size_t)pair * 512 + l * 8 + jh] = o;
    } else {
        int bb = b - 64;                       // 0..3
        int wv = threadIdx.x >> 6, lane = threadIdx.x & 63;
        for (int kk = 0; kk < 16; ++kk) {
            int k = bb * 64 + wv * 16 + kk;
            float4 wv4 = *(const float4*)(W + (size_t)k * 256 + 4 * lane);
            float4 a14 = *(const float4*)(a1 + 4 * lane);
            float4 a24 = *(const float4*)(a2 + 4 * lane);
            float d1 = wv4.x*a14.x + wv4.y*a14.y + wv4.z*a14.z + wv4.w*a14.w;
            float d2 = wv4.x*a24.x + wv4.y*a24.y + wv4.z*a24.z + wv4.w*a24.w;
            #pragma unroll
            for (int off = 32; off; off >>= 1) {
                d1 += __shfl_xor(d1, off);
                d2 += __shfl_xor(d2, off);
            }
            if (lane == 0) { w1[k] = d1; w2[k] = d2; }
        }
    }
}

// ======================= fused: LN + GEMM1 + softmax + PV ==================
// grid 256 (one b per block), 1024 threads = 16 waves/CU.
// xb as x:  [r 256][k 256] bf16, 512B rows, 16B-slot swizzle (k>>3)^(r&7)
// xb as hT: [c 256][j 256] bf16, 512B rows, 16B-slot swizzle (j>>3)^(c&7)
__global__ __launch_bounds__(1024)
void gat(const int* __restrict__ item_seq, const float* __restrict__ emb,
         const float* __restrict__ pos, const float* __restrict__ gamma,
         const float* __restrict__ beta, const float* __restrict__ w1,
         const float* __restrict__ w2, const u16* __restrict__ wfrag,
         float* __restrict__ out)
{
    __shared__ u16 xb[256 * 256];            // 128 KB
    __shared__ __align__(16) float s1s[256], s2s[256], mS[256];
    __shared__ __align__(16) float part[256][4];
    __shared__ float wmax[16];
    const int b    = blockIdx.x;
    const int tid  = threadIdx.x;
    const int lane = tid & 63, wid = tid >> 6, g = lane >> 4, li = lane & 15;
    const int iw_  = wid >> 2, nw = wid & 3;   // 4x4 wave grid

    // ---- Phase A: gather + LN + s1/s2 (wave-per-row, 2 rows per iter) -----
    {
        float4 g4  = *(const float4*)(gamma + 4 * lane);
        float4 b4  = *(const float4*)(beta  + 4 * lane);
        float4 w14 = *(const float4*)(w1    + 4 * lane);
        float4 w24 = *(const float4*)(w2    + 4 * lane);
        float4 u4, t4;
        u4.x = g4.x*w14.x; u4.y = g4.y*w14.y; u4.z = g4.z*w14.z; u4.w = g4.w*w14.w;
        t4.x = g4.x*w24.x; t4.y = g4.y*w24.y; t4.z = g4.z*w24.z; t4.w = g4.w*w24.w;
        float cA = u4.x + u4.y + u4.z + u4.w;                     // sum(gamma*w1)
        float cB = t4.x + t4.y + t4.z + t4.w;                     // sum(gamma*w2)
        float cC = b4.x*w14.x + b4.y*w14.y + b4.z*w14.z + b4.w*w14.w;  // beta.w1
        float cD = b4.x*w24.x + b4.y*w24.y + b4.z*w24.z + b4.w*w24.w;  // beta.w2
        #pragma unroll
        for (int off = 32; off; off >>= 1) {
            cA += __shfl_xor(cA, off); cB += __shfl_xor(cB, off);
            cC += __shfl_xor(cC, off); cD += __shfl_xor(cD, off);
        }
        float rm = -3.0e38f;
        #pragma unroll 2
        for (int it = 0; it < 8; ++it) {
            int rA = it * 32 + wid, rB = rA + 16;
            int gA = item_seq[b * 256 + rA];
            int gB = item_seq[b * 256 + rB];
            float4 eA = *(const float4*)(emb + (size_t)gA * 256 + 4 * lane);
            float4 pA = *(const float4*)(pos + (size_t)rA * 256 + 4 * lane);
            float4 eB = *(const float4*)(emb + (size_t)gB * 256 + 4 * lane);
            float4 pB = *(const float4*)(pos + (size_t)rB * 256 + 4 * lane);
            float4 vA, vB;
            vA.x = eA.x + pA.x; vA.y = eA.y + pA.y; vA.z = eA.z + pA.z; vA.w = eA.w + pA.w;
            vB.x = eB.x + pB.x; vB.y = eB.y + pB.y; vB.z = eB.z + pB.z; vB.w = eB.w + pB.w;
            float sa = vA.x + vA.y + vA.z + vA.w;
            float qa = vA.x*vA.x + vA.y*vA.y + vA.z*vA.z + vA.w*vA.w;
            float d1a = vA.x*u4.x + vA.y*u4.y + vA.z*u4.z + vA.w*u4.w;
            float d2a = vA.x*t4.x + vA.y*t4.y + vA.z*t4.z + vA.w*t4.w;
            float sb = vB.x + vB.y + vB.z + vB.w;
            float qb = vB.x*vB.x + vB.y*vB.y + vB.z*vB.z + vB.w*vB.w;
            float d1b = vB.x*u4.x + vB.y*u4.y + vB.z*u4.z + vB.w*u4.w;
            float d2b = vB.x*t4.x + vB.y*t4.y + vB.z*t4.z + vB.w*t4.w;
            #pragma unroll
            for (int off = 32; off; off >>= 1) {   // one chain, ILP-8
                sa  += __shfl_xor(sa,  off);  sb  += __shfl_xor(sb,  off);
                qa  += __shfl_xor(qa,  off);  qb  += __shfl_xor(qb,  off);
                d1a += __shfl_xor(d1a, off);  d1b += __shfl_xor(d1b, off);
                d2a += __shfl_xor(d2a, off);  d2b += __shfl_xor(d2b, off);
            }
            float muA = sa * (1.0f/256.0f);
            float rsA = rsqrtf(qa * (1.0f/256.0f) - muA*muA + 1e-12f);
            float muB = sb * (1.0f/256.0f);
            float rsB = rsqrtf(qb * (1.0f/256.0f) - muB*muB + 1e-12f);
            float s1A = rsA * (d1a - muA * cA) + cC;
            float s2A = rsA * (d2a - muA * cB) + cD;
            float s1B = rsB * (d1b - muB * cA) + cC;
            float s2B = rsB * (d2b - muB * cB) + cD;
            if (lane == 0) {
                s1s[rA] = s1A; s2s[rA] = s2A;
                s1s[rB] = s1B; s2s[rB] = s2B;
            }
            rm = fmaxf(rm, fmaxf(s2A, s2B));
            ushort4 oA, oB;
            oA.x = f2bf((vA.x - muA) * rsA * g4.x + b4.x);
            oA.y = f2bf((vA.y - muA) * rsA * g4.y + b4.y);
            oA.z = f2bf((vA.z - muA) * rsA * g4.z + b4.z);
            oA.w = f2bf((vA.w - muA) * rsA * g4.w + b4.w);
            oB.x = f2bf((vB.x - muB) * rsB * g4.x + b4.x);
            oB.y = f2bf((vB.y - muB) * rsB * g4.y + b4.y);
            oB.z = f2bf((vB.z - muB) * rsB * g4.z + b4.z);
            oB.w = f2bf((vB.w - muB) * rsB * g4.w + b4.w);
            int sl = (lane >> 1), sub = (lane & 1) * 4;
            *(ushort4*)&xb[rA * 256 + ((sl ^ (rA & 7)) << 3) + sub] = oA;
            *(ushort4*)&xb[rB * 256 + ((sl ^ (rB & 7)) << 3) + sub] = oB;
        }
        if (lane == 0) wmax[wid] = rm;
    }
    __syncthreads();   // bar1: xb(x), s1s, s2s, wmax ready

    // ---- stats: mi + per-quarter softmax denom (thread = (i, jq)) ---------
    {
        float s2m = wmax[0];
        #pragma unroll
        for (int k = 1; k < 16; ++k) s2m = fmaxf(s2m, wmax[k]);
        int i = tid >> 2, jq = tid & 3;
        float s1v = s1s[i];
        float mi  = lrelu(s1v + s2m);
        float sum = 0.f;
        const float4* sp = (const float4*)&s2s[jq * 64];
        #pragma unroll 4
        for (int j4 = 0; j4 < 16; ++j4) {
            float4 sv = sp[j4];
            sum += __builtin_amdgcn_exp2f((lrelu(s1v + sv.x) - mi) * L2E);
            sum += __builtin_amdgcn_exp2f((lrelu(s1v + sv.y) - mi) * L2E);
            sum += __builtin_amdgcn_exp2f((lrelu(s1v + sv.z) - mi) * L2E);
            sum += __builtin_amdgcn_exp2f((lrelu(s1v + sv.w) - mi) * L2E);
        }
        if (jq == 0) mS[i] = mi;
        part[i][jq] = sum;
    }
    // (no barrier needed: mS/part consumed after bar2+bar3)

    // ---- GEMM1: h = x @ W; B-frags = coalesced 1KB global loads -----------
    f32x4 acc[4][4];
    #pragma unroll
    for (int mt = 0; mt < 4; ++mt)
        #pragma unroll
        for (int nt = 0; nt < 4; ++nt)
            acc[mt][nt] = (f32x4){0.f, 0.f, 0.f, 0.f};

    #pragma unroll
    for (int ks = 0; ks < 8; ++ks) {
        short8 bf[4];
        #pragma unroll
        for (int nt = 0; nt < 4; ++nt)
            bf[nt] = *(const short8*)(wfrag
                       + ((size_t)(ks * 16 + nw * 4 + nt) * 64 + lane) * 8);
        #pragma unroll
        for (int mt = 0; mt < 4; ++mt) {
            int rl = iw_ * 64 + mt * 16 + li;
            short8 af = *(const short8*)&xb[rl * 256 + (((ks*4+g) ^ (rl & 7)) << 3)];
            #pragma unroll
            for (int nt = 0; nt < 4; ++nt)
                acc[mt][nt] = __builtin_amdgcn_mfma_f32_16x16x32_bf16(
                    af, bf[nt], acc[mt][nt], 0, 0, 0);
        }
    }
    __syncthreads();   // bar2: all x reads done; stats published

    // ---- transpose h into xb as hT[c][j] ----------------------------------
    #pragma unroll
    for (int mt = 0; mt < 4; ++mt)
        #pragma unroll
        for (int nt = 0; nt < 4; ++nt) {
            int c  = nw * 64 + nt * 16 + li;
            int i0 = iw_ * 64 + mt * 16 + 4 * g;
            uint2 o;
            o.x = pk2(acc[mt][nt][0], acc[mt][nt][1]);
            o.y = pk2(acc[mt][nt][2], acc[mt][nt][3]);
            *(uint2*)&xb[c * 256 + (((i0 >> 3) ^ (c & 7)) << 3) + (i0 & 7)] = o;
        }
    __syncthreads();   // bar3: hT ready

    // ---- PV: out = P @ h, P built in-register -----------------------------
    {
        f32x4 oacc[4][4];
        #pragma unroll
        for (int mt = 0; mt < 4; ++mt)
            #pragma unroll
            for (int nt = 0; nt < 4; ++nt)
                oacc[mt][nt] = (f32x4){0.f, 0.f, 0.f, 0.f};

        float s1r[4], mv[4], lv[4];
        #pragma unroll
        for (int mt = 0; mt < 4; ++mt) {
            int i = iw_ * 64 + mt * 16 + li;
            s1r[mt] = s1s[i];
            mv[mt]  = mS[i];
            lv[mt]  = 1.0f / (part[i][0] + part[i][1] + part[i][2] + part[i][3]);
        }

        #pragma unroll
        for (int js = 0; js < 8; ++js) {
            float s2l[8];
            #pragma unroll
            for (int jj = 0; jj < 8; ++jj) s2l[jj] = s2s[js * 32 + g * 8 + jj];

            short8 pfr[4];
            #pragma unroll
            for (int mt = 0; mt < 4; ++mt) {
                union { unsigned int u[4]; short8 s; } pk;
                #pragma unroll
                for (int q2 = 0; q2 < 4; ++q2) {
                    float e0 = lrelu(s1r[mt] + s2l[2 * q2]);
                    float e1 = lrelu(s1r[mt] + s2l[2 * q2 + 1]);
                    float p0 = __builtin_amdgcn_exp2f((e0 - mv[mt]) * L2E) * lv[mt];
                    float p1 = __builtin_amdgcn_exp2f((e1 - mv[mt]) * L2E) * lv[mt];
                    pk.u[q2] = pk2(p0, p1);
                }
                pfr[mt] = pk.s;
            }
            #pragma unroll
            for (int nt = 0; nt < 4; ++nt) {
                int cl = nw * 64 + nt * 16 + li;
                short8 vf = *(const short8*)&xb[cl * 256
                              + (((js * 4 + g) ^ (cl & 7)) << 3)];
                #pragma unroll
                for (int mt = 0; mt < 4; ++mt)
                    oacc[mt][nt] = __builtin_amdgcn_mfma_f32_16x16x32_bf16(
                        pfr[mt], vf, oacc[mt][nt], 0, 0, 0);
            }
        }

        size_t ob = (size_t)b * (256 * 256);
        #pragma unroll
        for (int mt = 0; mt < 4; ++mt)
            #pragma unroll
            for (int nt = 0; nt < 4; ++nt) {
                int c  = nw * 64 + nt * 16 + li;
                int i0 = iw_ * 64 + mt * 16 + 4 * g;
                #pragma unroll
                for (int q2 = 0; q2 < 4; ++q2)
                    out[ob + (size_t)(i0 + q2) * 256 + c] = oacc[mt][nt][q2];
            }
    }
}

extern "C" void kernel_launch(void* const* d_in, const int* in_sizes, int n_in,
                              void* d_out, int out_size, void* d_ws, size_t ws_size,
                              hipStream_t stream) {
    (void)in_sizes; (void)n_in; (void)out_size; (void)ws_size;
    const int*   seq   = (const int*)d_in[0];
    const float* emb   = (const float*)d_in[1];
    const float* pos   = (const float*)d_in[2];
    const float* W     = (const float*)d_in[3];
    const float* a1    = (const float*)d_in[4];
    const float* a2    = (const float*)d_in[5];
    const float* gamma = (const float*)d_in[6];
    const float* beta  = (const float*)d_in[7];

    char* ws = (char*)d_ws;
    u16*   wfrag = (u16*)ws;                     // 131072 B
    float* w1    = (float*)(ws + 131072);        // 1 KB
    float* w2    = (float*)(ws + 132096);        // 1 KB

    hipLaunchKernelGGL(prep, dim3(68), dim3(256), 0, stream, W, a1, a2, wfrag, w1, w2);
    hipLaunchKernelGGL(gat, dim3(256), dim3(1024), 0, stream,
                       seq, emb, pos, gamma, beta, w1, w2, wfrag, (float*)d_out);
}

// Round 10
// 60.334 us; speedup vs baseline: 2.5230x; 1.1730x over previous
//
#include <hip/hip_runtime.h>
#include <hip/hip_bf16.h>

#define ALPHA  0.2f
#define L2E    1.4426950408889634f

typedef __attribute__((ext_vector_type(8))) short  short8;
typedef __attribute__((ext_vector_type(4))) float  f32x4;
typedef unsigned short u16;

__device__ __forceinline__ u16 f2bf(float f) {
    union { float f; unsigned int u; } v; v.f = f;
    unsigned int r = (v.u + 0x7FFFu + ((v.u >> 16) & 1u)) >> 16;   // RNE
    return (u16)r;
}
__device__ __forceinline__ unsigned pk2(float a, float b) {   // lo=a, hi=b
    return (unsigned)f2bf(a) | ((unsigned)f2bf(b) << 16);
}
__device__ __forceinline__ float lrelu(float x) { return fmaxf(x, ALPHA * x); }

// ---- prep: W -> wfrag[pair 128][lane 64][8] (B-fragment-contiguous bf16),
//      pair = ks*16 + cblock; also w1 = W@a1, w2 = W@a2.
__global__ void prep(const float* __restrict__ W, const float* __restrict__ a1,
                     const float* __restrict__ a2, u16* __restrict__ wfrag,
                     float* __restrict__ w1, float* __restrict__ w2) {
    int b = blockIdx.x;
    if (b < 64) {
        int t    = threadIdx.x;
        int pair = b * 2 + (t >> 7);
        int l    = (t >> 1) & 63;
        int jh   = (t & 1) * 4;
        int ks   = pair >> 4, cb = pair & 15;
        int c  = cb * 16 + (l & 15);
        int k0 = ks * 32 + (l >> 4) * 8 + jh;
        ushort4 o;
        o.x = f2bf(W[(size_t)(k0 + 0) * 256 + c]);
        o.y = f2bf(W[(size_t)(k0 + 1) * 256 + c]);
        o.z = f2bf(W[(size_t)(k0 + 2) * 256 + c]);
        o.w = f2bf(W[(size_t)(k0 + 3) * 256 + c]);
        *(ushort4*)&wfrag[(size_t)pair * 512 + l * 8 + jh] = o;
    } else {
        int bb = b - 64;                       // 0..3
        int wv = threadIdx.x >> 6, lane = threadIdx.x & 63;
        for (int kk = 0; kk < 16; ++kk) {
            int k = bb * 64 + wv * 16 + kk;
            float4 wv4 = *(const float4*)(W + (size_t)k * 256 + 4 * lane);
            float4 a14 = *(const float4*)(a1 + 4 * lane);
            float4 a24 = *(const float4*)(a2 + 4 * lane);
            float d1 = wv4.x*a14.x + wv4.y*a14.y + wv4.z*a14.z + wv4.w*a14.w;
            float d2 = wv4.x*a24.x + wv4.y*a24.y + wv4.z*a24.z + wv4.w*a24.w;
            #pragma unroll
            for (int off = 32; off; off >>= 1) {
                d1 += __shfl_xor(d1, off);
                d2 += __shfl_xor(d2, off);
            }
            if (lane == 0) { w1[k] = d1; w2[k] = d2; }
        }
    }
}

// ======================= fused: LN + GEMM1 + softmax + PV ==================
// grid 256, 1024 threads = 16 waves/CU. s1s/s2s/mS stored PRE-SCALED by L2E.
__global__ __launch_bounds__(1024)
void gat(const int* __restrict__ item_seq, const float* __restrict__ emb,
         const float* __restrict__ pos, const float* __restrict__ gamma,
         const float* __restrict__ beta, const float* __restrict__ w1,
         const float* __restrict__ w2, const u16* __restrict__ wfrag,
         float* __restrict__ out)
{
    __shared__ u16 xb[256 * 256];            // 128 KB
    __shared__ __align__(16) float s1s[256], s2s[256], mS[256];
    __shared__ __align__(16) float part[256][4];
    __shared__ float wmax[16];
    const int b    = blockIdx.x;
    const int tid  = threadIdx.x;
    const int lane = tid & 63, wid = tid >> 6, g = lane >> 4, li = lane & 15;
    const int iw_  = wid >> 2, nw = wid & 3;   // 4x4 wave grid (Phase A + GEMM1)

    // ---- Phase A: gather + LN + s1/s2 (wave-per-row, 2 rows per iter) -----
    {
        float4 g4  = *(const float4*)(gamma + 4 * lane);
        float4 b4  = *(const float4*)(beta  + 4 * lane);
        float4 w14 = *(const float4*)(w1    + 4 * lane);
        float4 w24 = *(const float4*)(w2    + 4 * lane);
        float4 u4, t4;
        u4.x = g4.x*w14.x; u4.y = g4.y*w14.y; u4.z = g4.z*w14.z; u4.w = g4.w*w14.w;
        t4.x = g4.x*w24.x; t4.y = g4.y*w24.y; t4.z = g4.z*w24.z; t4.w = g4.w*w24.w;
        float cA = u4.x + u4.y + u4.z + u4.w;                     // sum(gamma*w1)
        float cB = t4.x + t4.y + t4.z + t4.w;                     // sum(gamma*w2)
        float cC = b4.x*w14.x + b4.y*w14.y + b4.z*w14.z + b4.w*w14.w;  // beta.w1
        float cD = b4.x*w24.x + b4.y*w24.y + b4.z*w24.z + b4.w*w24.w;  // beta.w2
        #pragma unroll
        for (int off = 32; off; off >>= 1) {
            cA += __shfl_xor(cA, off); cB += __shfl_xor(cB, off);
            cC += __shfl_xor(cC, off); cD += __shfl_xor(cD, off);
        }
        float rm = -3.0e38f;
        #pragma unroll 2
        for (int it = 0; it < 8; ++it) {
            int rA = it * 32 + wid, rB = rA + 16;
            int gA = item_seq[b * 256 + rA];
            int gB = item_seq[b * 256 + rB];
            float4 eA = *(const float4*)(emb + (size_t)gA * 256 + 4 * lane);
            float4 pA = *(const float4*)(pos + (size_t)rA * 256 + 4 * lane);
            float4 eB = *(const float4*)(emb + (size_t)gB * 256 + 4 * lane);
            float4 pB = *(const float4*)(pos + (size_t)rB * 256 + 4 * lane);
            float4 vA, vB;
            vA.x = eA.x + pA.x; vA.y = eA.y + pA.y; vA.z = eA.z + pA.z; vA.w = eA.w + pA.w;
            vB.x = eB.x + pB.x; vB.y = eB.y + pB.y; vB.z = eB.z + pB.z; vB.w = eB.w + pB.w;
            float sa = vA.x + vA.y + vA.z + vA.w;
            float qa = vA.x*vA.x + vA.y*vA.y + vA.z*vA.z + vA.w*vA.w;
            float d1a = vA.x*u4.x + vA.y*u4.y + vA.z*u4.z + vA.w*u4.w;
            float d2a = vA.x*t4.x + vA.y*t4.y + vA.z*t4.z + vA.w*t4.w;
            float sb = vB.x + vB.y + vB.z + vB.w;
            float qb = vB.x*vB.x + vB.y*vB.y + vB.z*vB.z + vB.w*vB.w;
            float d1b = vB.x*u4.x + vB.y*u4.y + vB.z*u4.z + vB.w*u4.w;
            float d2b = vB.x*t4.x + vB.y*t4.y + vB.z*t4.z + vB.w*t4.w;
            #pragma unroll
            for (int off = 32; off; off >>= 1) {   // one chain, ILP-8
                sa  += __shfl_xor(sa,  off);  sb  += __shfl_xor(sb,  off);
                qa  += __shfl_xor(qa,  off);  qb  += __shfl_xor(qb,  off);
                d1a += __shfl_xor(d1a, off);  d1b += __shfl_xor(d1b, off);
                d2a += __shfl_xor(d2a, off);  d2b += __shfl_xor(d2b, off);
            }
            float muA = sa * (1.0f/256.0f);
            float rsA = rsqrtf(qa * (1.0f/256.0f) - muA*muA + 1e-12f);
            float muB = sb * (1.0f/256.0f);
            float rsB = rsqrtf(qb * (1.0f/256.0f) - muB*muB + 1e-12f);
            float s1A = (rsA * (d1a - muA * cA) + cC) * L2E;   // pre-scaled
            float s2A = (rsA * (d2a - muA * cB) + cD) * L2E;
            float s1B = (rsB * (d1b - muB * cA) + cC) * L2E;
            float s2B = (rsB * (d2b - muB * cB) + cD) * L2E;
            if (lane == 0) {
                s1s[rA] = s1A; s2s[rA] = s2A;
                s1s[rB] = s1B; s2s[rB] = s2B;
            }
            rm = fmaxf(rm, fmaxf(s2A, s2B));
            uint2 oA, oB;
            oA.x = pk2((vA.x - muA) * rsA * g4.x + b4.x,
                       (vA.y - muA) * rsA * g4.y + b4.y);
            oA.y = pk2((vA.z - muA) * rsA * g4.z + b4.z,
                       (vA.w - muA) * rsA * g4.w + b4.w);
            oB.x = pk2((vB.x - muB) * rsB * g4.x + b4.x,
                       (vB.y - muB) * rsB * g4.y + b4.y);
            oB.y = pk2((vB.z - muB) * rsB * g4.z + b4.z,
                       (vB.w - muB) * rsB * g4.w + b4.w);
            int sl = (lane >> 1), sub = (lane & 1) * 4;
            *(uint2*)&xb[rA * 256 + ((sl ^ (rA & 7)) << 3) + sub] = oA;
            *(uint2*)&xb[rB * 256 + ((sl ^ (rB & 7)) << 3) + sub] = oB;
        }
        if (lane == 0) wmax[wid] = rm;
    }
    __syncthreads();   // bar1: xb(x), s1s, s2s, wmax ready

    // ---- stats: miL + per-quarter softmax denom (thread = (i, jq)) --------
    {
        float s2m = wmax[0];
        #pragma unroll
        for (int k = 1; k < 16; ++k) s2m = fmaxf(s2m, wmax[k]);
        int i = tid >> 2, jq = tid & 3;
        float s1v = s1s[i];
        float mi  = lrelu(s1v + s2m);          // scaled domain
        float aB0 = s1v - mi;
        float bB0 = ALPHA * s1v - mi;
        float sum = 0.f;
        const float4* sp = (const float4*)&s2s[jq * 64];
        #pragma unroll 4
        for (int j4 = 0; j4 < 16; ++j4) {
            float4 sv = sp[j4];
            sum += __builtin_amdgcn_exp2f(fmaxf(aB0 + sv.x, fmaf(ALPHA, sv.x, bB0)));
            sum += __builtin_amdgcn_exp2f(fmaxf(aB0 + sv.y, fmaf(ALPHA, sv.y, bB0)));
            sum += __builtin_amdgcn_exp2f(fmaxf(aB0 + sv.z, fmaf(ALPHA, sv.z, bB0)));
            sum += __builtin_amdgcn_exp2f(fmaxf(aB0 + sv.w, fmaf(ALPHA, sv.w, bB0)));
        }
        if (jq == 0) mS[i] = mi;
        part[i][jq] = sum;
    }

    // ---- GEMM1: h = x @ W; B-frags = coalesced 1KB global loads -----------
    f32x4 acc[4][4];
    #pragma unroll
    for (int mt = 0; mt < 4; ++mt)
        #pragma unroll
        for (int nt = 0; nt < 4; ++nt)
            acc[mt][nt] = (f32x4){0.f, 0.f, 0.f, 0.f};

    #pragma unroll
    for (int ks = 0; ks < 8; ++ks) {
        short8 bf[4];
        #pragma unroll
        for (int nt = 0; nt < 4; ++nt)
            bf[nt] = *(const short8*)(wfrag
                       + ((size_t)(ks * 16 + nw * 4 + nt) * 64 + lane) * 8);
        #pragma unroll
        for (int mt = 0; mt < 4; ++mt) {
            int rl = iw_ * 64 + mt * 16 + li;
            short8 af = *(const short8*)&xb[rl * 256 + (((ks*4+g) ^ (rl & 7)) << 3)];
            #pragma unroll
            for (int nt = 0; nt < 4; ++nt)
                acc[mt][nt] = __builtin_amdgcn_mfma_f32_16x16x32_bf16(
                    af, bf[nt], acc[mt][nt], 0, 0, 0);
        }
    }
    __syncthreads();   // bar2: all x reads done; stats published

    // ---- transpose h into xb as hT[c][j] ----------------------------------
    #pragma unroll
    for (int mt = 0; mt < 4; ++mt)
        #pragma unroll
        for (int nt = 0; nt < 4; ++nt) {
            int c  = nw * 64 + nt * 16 + li;
            int i0 = iw_ * 64 + mt * 16 + 4 * g;
            uint2 o;
            o.x = pk2(acc[mt][nt][0], acc[mt][nt][1]);
            o.y = pk2(acc[mt][nt][2], acc[mt][nt][3]);
            *(uint2*)&xb[c * 256 + (((i0 >> 3) ^ (c & 7)) << 3) + (i0 & 7)] = o;
        }
    __syncthreads();   // bar3: hT ready

    // ---- PV: out = P @ h; wave grid 8 (i) x 2 (c) — redundancy 2 ----------
    {
        const int ig2 = wid >> 1;   // i-group: 32 rows
        const int ng2 = wid & 1;    // c-group: 128 cols
        f32x4 oacc[2][8];
        #pragma unroll
        for (int mt = 0; mt < 2; ++mt)
            #pragma unroll
            for (int nt = 0; nt < 8; ++nt)
                oacc[mt][nt] = (f32x4){0.f, 0.f, 0.f, 0.f};

        float aBase[2], bBase[2];
        #pragma unroll
        for (int mt = 0; mt < 2; ++mt) {
            int i = ig2 * 32 + mt * 16 + li;
            float lsum = part[i][0] + part[i][1] + part[i][2] + part[i][3];
            float Mi = mS[i] + __log2f(lsum);
            float s1v = s1s[i];
            aBase[mt] = s1v - Mi;
            bBase[mt] = ALPHA * s1v - Mi;
        }

        #pragma unroll
        for (int js = 0; js < 8; ++js) {
            float4 sv0 = *(const float4*)&s2s[js * 32 + g * 8];
            float4 sv1 = *(const float4*)&s2s[js * 32 + g * 8 + 4];
            float s2l[8] = {sv0.x, sv0.y, sv0.z, sv0.w, sv1.x, sv1.y, sv1.z, sv1.w};

            short8 pfr[2];
            #pragma unroll
            for (int mt = 0; mt < 2; ++mt) {
                union { unsigned int u[4]; short8 s; } pk;
                #pragma unroll
                for (int q2 = 0; q2 < 4; ++q2) {
                    float sA = s2l[2 * q2], sB = s2l[2 * q2 + 1];
                    float p0 = __builtin_amdgcn_exp2f(
                        fmaxf(aBase[mt] + sA, fmaf(ALPHA, sA, bBase[mt])));
                    float p1 = __builtin_amdgcn_exp2f(
                        fmaxf(aBase[mt] + sB, fmaf(ALPHA, sB, bBase[mt])));
                    pk.u[q2] = pk2(p0, p1);
                }
                pfr[mt] = pk.s;
            }
            #pragma unroll
            for (int nt = 0; nt < 8; ++nt) {
                int cl = ng2 * 128 + nt * 16 + li;
                short8 vf = *(const short8*)&xb[cl * 256
                              + (((js * 4 + g) ^ (cl & 7)) << 3)];
                #pragma unroll
                for (int mt = 0; mt < 2; ++mt)
                    oacc[mt][nt] = __builtin_amdgcn_mfma_f32_16x16x32_bf16(
                        pfr[mt], vf, oacc[mt][nt], 0, 0, 0);
            }
        }

        size_t ob = (size_t)b * (256 * 256);
        #pragma unroll
        for (int mt = 0; mt < 2; ++mt)
            #pragma unroll
            for (int nt = 0; nt < 8; ++nt) {
                int c  = ng2 * 128 + nt * 16 + li;
                int i0 = ig2 * 32 + mt * 16 + 4 * g;
                #pragma unroll
                for (int q2 = 0; q2 < 4; ++q2)
                    out[ob + (size_t)(i0 + q2) * 256 + c] = oacc[mt][nt][q2];
            }
    }
}

extern "C" void kernel_launch(void* const* d_in, const int* in_sizes, int n_in,
                              void* d_out, int out_size, void* d_ws, size_t ws_size,
                              hipStream_t stream) {
    (void)in_sizes; (void)n_in; (void)out_size; (void)ws_size;
    const int*   seq   = (const int*)d_in[0];
    const float* emb   = (const float*)d_in[1];
    const float* pos   = (const float*)d_in[2];
    const float* W     = (const float*)d_in[3];
    const float* a1    = (const float*)d_in[4];
    const float* a2    = (const float*)d_in[5];
    const float* gamma = (const float*)d_in[6];
    const float* beta  = (const float*)d_in[7];

    char* ws = (char*)d_ws;
    u16*   wfrag = (u16*)ws;                     // 131072 B
    float* w1    = (float*)(ws + 131072);        // 1 KB
    float* w2    = (float*)(ws + 132096);        // 1 KB

    hipLaunchKernelGGL(prep, dim3(68), dim3(256), 0, stream, W, a1, a2, wfrag, w1, w2);
    hipLaunchKernelGGL(gat, dim3(256), dim3(1024), 0, stream,
                       seq, emb, pos, gamma, beta, w1, w2, wfrag, (float*)d_out);
}

// Round 11
// 59.251 us; speedup vs baseline: 2.5691x; 1.0183x over previous
//
#include <hip/hip_runtime.h>
#include <hip/hip_bf16.h>

#define ALPHA  0.2f
#define L2E    1.4426950408889634f

typedef __attribute__((ext_vector_type(8))) short  short8;
typedef __attribute__((ext_vector_type(4))) float  f32x4;
typedef unsigned short u16;

__device__ __forceinline__ u16 f2bf(float f) {
    union { __hip_bfloat16 h; u16 u; } v;
    v.h = __float2bfloat16(f);
    return v.u;
}
__device__ __forceinline__ unsigned pk2(float a, float b) {   // lo=a, hi=b
    union { __hip_bfloat162 h2; unsigned u; } v;
    float2 f2; f2.x = a; f2.y = b;
    v.h2 = __float22bfloat162_rn(f2);
    return v.u;
}
__device__ __forceinline__ float lrelu(float x) { return fmaxf(x, ALPHA * x); }

// ---- prep: W -> wfrag[pair 128][lane 64][8] (B-fragment-contiguous bf16),
//      pair = ks*16 + cblock; also w1 = W@a1, w2 = W@a2.
__global__ void prep(const float* __restrict__ W, const float* __restrict__ a1,
                     const float* __restrict__ a2, u16* __restrict__ wfrag,
                     float* __restrict__ w1, float* __restrict__ w2) {
    int b = blockIdx.x;
    if (b < 64) {
        int t    = threadIdx.x;
        int pair = b * 2 + (t >> 7);
        int l    = (t >> 1) & 63;
        int jh   = (t & 1) * 4;
        int ks   = pair >> 4, cb = pair & 15;
        int c  = cb * 16 + (l & 15);
        int k0 = ks * 32 + (l >> 4) * 8 + jh;
        ushort4 o;
        o.x = f2bf(W[(size_t)(k0 + 0) * 256 + c]);
        o.y = f2bf(W[(size_t)(k0 + 1) * 256 + c]);
        o.z = f2bf(W[(size_t)(k0 + 2) * 256 + c]);
        o.w = f2bf(W[(size_t)(k0 + 3) * 256 + c]);
        *(ushort4*)&wfrag[(size_t)pair * 512 + l * 8 + jh] = o;
    } else {
        int bb = b - 64;                       // 0..3
        int wv = threadIdx.x >> 6, lane = threadIdx.x & 63;
        for (int kk = 0; kk < 16; ++kk) {
            int k = bb * 64 + wv * 16 + kk;
            float4 wv4 = *(const float4*)(W + (size_t)k * 256 + 4 * lane);
            float4 a14 = *(const float4*)(a1 + 4 * lane);
            float4 a24 = *(const float4*)(a2 + 4 * lane);
            float d1 = wv4.x*a14.x + wv4.y*a14.y + wv4.z*a14.z + wv4.w*a14.w;
            float d2 = wv4.x*a24.x + wv4.y*a24.y + wv4.z*a24.z + wv4.w*a24.w;
            #pragma unroll
            for (int off = 32; off; off >>= 1) {
                d1 += __shfl_xor(d1, off);
                d2 += __shfl_xor(d2, off);
            }
            if (lane == 0) { w1[k] = d1; w2[k] = d2; }
        }
    }
}

// ======================= fused: LN + GEMM1 + softmax + PV ==================
// grid 256, 1024 threads = 16 waves/CU. s1s/s2s/mS stored PRE-SCALED by L2E.
__global__ __launch_bounds__(1024)
void gat(const int* __restrict__ item_seq, const float* __restrict__ emb,
         const float* __restrict__ pos, const float* __restrict__ gamma,
         const float* __restrict__ beta, const float* __restrict__ w1,
         const float* __restrict__ w2, const u16* __restrict__ wfrag,
         float* __restrict__ out)
{
    __shared__ u16 xb[256 * 256];            // 128 KB
    __shared__ __align__(16) float s1s[256], s2s[256], mS[256];
    __shared__ __align__(16) float part[256][4];
    __shared__ float wmax[16];
    const int b    = blockIdx.x;
    const int tid  = threadIdx.x;
    const int lane = tid & 63, wid = tid >> 6, g = lane >> 4, li = lane & 15;
    const int iw_  = wid >> 2, nw = wid & 3;   // 4x4 wave grid (Phase A + GEMM1)

    // ---- Phase A: gather + LN + s1/s2 (wave-per-row, 2 rows per iter) -----
    {
        float4 g4  = *(const float4*)(gamma + 4 * lane);
        float4 b4  = *(const float4*)(beta  + 4 * lane);
        float4 w14 = *(const float4*)(w1    + 4 * lane);
        float4 w24 = *(const float4*)(w2    + 4 * lane);
        float4 u4, t4;
        u4.x = g4.x*w14.x; u4.y = g4.y*w14.y; u4.z = g4.z*w14.z; u4.w = g4.w*w14.w;
        t4.x = g4.x*w24.x; t4.y = g4.y*w24.y; t4.z = g4.z*w24.z; t4.w = g4.w*w24.w;
        float cA = u4.x + u4.y + u4.z + u4.w;                     // sum(gamma*w1)
        float cB = t4.x + t4.y + t4.z + t4.w;                     // sum(gamma*w2)
        float cC = b4.x*w14.x + b4.y*w14.y + b4.z*w14.z + b4.w*w14.w;  // beta.w1
        float cD = b4.x*w24.x + b4.y*w24.y + b4.z*w24.z + b4.w*w24.w;  // beta.w2
        #pragma unroll
        for (int off = 32; off; off >>= 1) {
            cA += __shfl_xor(cA, off); cB += __shfl_xor(cB, off);
            cC += __shfl_xor(cC, off); cD += __shfl_xor(cD, off);
        }
        float rm = -3.0e38f;
        #pragma unroll 2
        for (int it = 0; it < 8; ++it) {
            int rA = it * 32 + wid, rB = rA + 16;
            int gA = item_seq[b * 256 + rA];
            int gB = item_seq[b * 256 + rB];
            float4 eA = *(const float4*)(emb + (size_t)gA * 256 + 4 * lane);
            float4 pA = *(const float4*)(pos + (size_t)rA * 256 + 4 * lane);
            float4 eB = *(const float4*)(emb + (size_t)gB * 256 + 4 * lane);
            float4 pB = *(const float4*)(pos + (size_t)rB * 256 + 4 * lane);
            float4 vA, vB;
            vA.x = eA.x + pA.x; vA.y = eA.y + pA.y; vA.z = eA.z + pA.z; vA.w = eA.w + pA.w;
            vB.x = eB.x + pB.x; vB.y = eB.y + pB.y; vB.z = eB.z + pB.z; vB.w = eB.w + pB.w;
            float sa = vA.x + vA.y + vA.z + vA.w;
            float qa = vA.x*vA.x + vA.y*vA.y + vA.z*vA.z + vA.w*vA.w;
            float d1a = vA.x*u4.x + vA.y*u4.y + vA.z*u4.z + vA.w*u4.w;
            float d2a = vA.x*t4.x + vA.y*t4.y + vA.z*t4.z + vA.w*t4.w;
            float sb = vB.x + vB.y + vB.z + vB.w;
            float qb = vB.x*vB.x + vB.y*vB.y + vB.z*vB.z + vB.w*vB.w;
            float d1b = vB.x*u4.x + vB.y*u4.y + vB.z*u4.z + vB.w*u4.w;
            float d2b = vB.x*t4.x + vB.y*t4.y + vB.z*t4.z + vB.w*t4.w;
            #pragma unroll
            for (int off = 32; off; off >>= 1) {   // one chain, ILP-8
                sa  += __shfl_xor(sa,  off);  sb  += __shfl_xor(sb,  off);
                qa  += __shfl_xor(qa,  off);  qb  += __shfl_xor(qb,  off);
                d1a += __shfl_xor(d1a, off);  d1b += __shfl_xor(d1b, off);
                d2a += __shfl_xor(d2a, off);  d2b += __shfl_xor(d2b, off);
            }
            float muA = sa * (1.0f/256.0f);
            float rsA = rsqrtf(qa * (1.0f/256.0f) - muA*muA + 1e-12f);
            float muB = sb * (1.0f/256.0f);
            float rsB = rsqrtf(qb * (1.0f/256.0f) - muB*muB + 1e-12f);
            float s1A = (rsA * (d1a - muA * cA) + cC) * L2E;   // pre-scaled
            float s2A = (rsA * (d2a - muA * cB) + cD) * L2E;
            float s1B = (rsB * (d1b - muB * cA) + cC) * L2E;
            float s2B = (rsB * (d2b - muB * cB) + cD) * L2E;
            if (lane == 0) {
                s1s[rA] = s1A; s2s[rA] = s2A;
                s1s[rB] = s1B; s2s[rB] = s2B;
            }
            rm = fmaxf(rm, fmaxf(s2A, s2B));
            uint2 oA, oB;
            oA.x = pk2((vA.x - muA) * rsA * g4.x + b4.x,
                       (vA.y - muA) * rsA * g4.y + b4.y);
            oA.y = pk2((vA.z - muA) * rsA * g4.z + b4.z,
                       (vA.w - muA) * rsA * g4.w + b4.w);
            oB.x = pk2((vB.x - muB) * rsB * g4.x + b4.x,
                       (vB.y - muB) * rsB * g4.y + b4.y);
            oB.y = pk2((vB.z - muB) * rsB * g4.z + b4.z,
                       (vB.w - muB) * rsB * g4.w + b4.w);
            int sl = (lane >> 1), sub = (lane & 1) * 4;
            *(uint2*)&xb[rA * 256 + ((sl ^ (rA & 7)) << 3) + sub] = oA;
            *(uint2*)&xb[rB * 256 + ((sl ^ (rB & 7)) << 3) + sub] = oB;
        }
        if (lane == 0) wmax[wid] = rm;
    }
    __syncthreads();   // bar1: xb(x), s1s, s2s, wmax ready

    // ---- stats: miL + per-quarter softmax denom (thread = (i, jq)) --------
    {
        float s2m = wmax[0];
        #pragma unroll
        for (int k = 1; k < 16; ++k) s2m = fmaxf(s2m, wmax[k]);
        int i = tid >> 2, jq = tid & 3;
        float s1v = s1s[i];
        float mi  = lrelu(s1v + s2m);          // scaled domain
        float aB0 = s1v - mi;
        float bB0 = ALPHA * s1v - mi;
        float sum = 0.f;
        const float4* sp = (const float4*)&s2s[jq * 64];
        #pragma unroll 4
        for (int j4 = 0; j4 < 16; ++j4) {
            float4 sv = sp[j4];
            sum += __builtin_amdgcn_exp2f(fmaxf(aB0 + sv.x, fmaf(ALPHA, sv.x, bB0)));
            sum += __builtin_amdgcn_exp2f(fmaxf(aB0 + sv.y, fmaf(ALPHA, sv.y, bB0)));
            sum += __builtin_amdgcn_exp2f(fmaxf(aB0 + sv.z, fmaf(ALPHA, sv.z, bB0)));
            sum += __builtin_amdgcn_exp2f(fmaxf(aB0 + sv.w, fmaf(ALPHA, sv.w, bB0)));
        }
        if (jq == 0) mS[i] = mi;
        part[i][jq] = sum;
    }

    // ---- GEMM1: h = x @ W; B-frags = coalesced 1KB global loads -----------
    f32x4 acc[4][4];
    #pragma unroll
    for (int mt = 0; mt < 4; ++mt)
        #pragma unroll
        for (int nt = 0; nt < 4; ++nt)
            acc[mt][nt] = (f32x4){0.f, 0.f, 0.f, 0.f};

    #pragma unroll
    for (int ks = 0; ks < 8; ++ks) {
        short8 bf[4];
        #pragma unroll
        for (int nt = 0; nt < 4; ++nt)
            bf[nt] = *(const short8*)(wfrag
                       + ((size_t)(ks * 16 + nw * 4 + nt) * 64 + lane) * 8);
        #pragma unroll
        for (int mt = 0; mt < 4; ++mt) {
            int rl = iw_ * 64 + mt * 16 + li;
            short8 af = *(const short8*)&xb[rl * 256 + (((ks*4+g) ^ (rl & 7)) << 3)];
            #pragma unroll
            for (int nt = 0; nt < 4; ++nt)
                acc[mt][nt] = __builtin_amdgcn_mfma_f32_16x16x32_bf16(
                    af, bf[nt], acc[mt][nt], 0, 0, 0);
        }
    }
    __syncthreads();   // bar2: all x reads done; stats published

    // ---- transpose h into xb as hT[c][j] ----------------------------------
    #pragma unroll
    for (int mt = 0; mt < 4; ++mt)
        #pragma unroll
        for (int nt = 0; nt < 4; ++nt) {
            int c  = nw * 64 + nt * 16 + li;
            int i0 = iw_ * 64 + mt * 16 + 4 * g;
            uint2 o;
            o.x = pk2(acc[mt][nt][0], acc[mt][nt][1]);
            o.y = pk2(acc[mt][nt][2], acc[mt][nt][3]);
            *(uint2*)&xb[c * 256 + (((i0 >> 3) ^ (c & 7)) << 3) + (i0 & 7)] = o;
        }
    __syncthreads();   // bar3: hT ready

    // ---- PV: out = P @ h; wave grid 8 (i) x 2 (c) — redundancy 2 ----------
    {
        const int ig2 = wid >> 1;   // i-group: 32 rows
        const int ng2 = wid & 1;    // c-group: 128 cols
        f32x4 oacc[2][8];
        #pragma unroll
        for (int mt = 0; mt < 2; ++mt)
            #pragma unroll
            for (int nt = 0; nt < 8; ++nt)
                oacc[mt][nt] = (f32x4){0.f, 0.f, 0.f, 0.f};

        float aBase[2], bBase[2];
        #pragma unroll
        for (int mt = 0; mt < 2; ++mt) {
            int i = ig2 * 32 + mt * 16 + li;
            float lsum = part[i][0] + part[i][1] + part[i][2] + part[i][3];
            float Mi = mS[i] + __log2f(lsum);
            float s1v = s1s[i];
            aBase[mt] = s1v - Mi;
            bBase[mt] = ALPHA * s1v - Mi;
        }

        #pragma unroll
        for (int js = 0; js < 8; ++js) {
            float4 sv0 = *(const float4*)&s2s[js * 32 + g * 8];
            float4 sv1 = *(const float4*)&s2s[js * 32 + g * 8 + 4];
            float s2l[8] = {sv0.x, sv0.y, sv0.z, sv0.w, sv1.x, sv1.y, sv1.z, sv1.w};

            short8 pfr[2];
            #pragma unroll
            for (int mt = 0; mt < 2; ++mt) {
                union { unsigned int u[4]; short8 s; } pk;
                #pragma unroll
                for (int q2 = 0; q2 < 4; ++q2) {
                    float sA = s2l[2 * q2], sB = s2l[2 * q2 + 1];
                    float p0 = __builtin_amdgcn_exp2f(
                        fmaxf(aBase[mt] + sA, fmaf(ALPHA, sA, bBase[mt])));
                    float p1 = __builtin_amdgcn_exp2f(
                        fmaxf(aBase[mt] + sB, fmaf(ALPHA, sB, bBase[mt])));
                    pk.u[q2] = pk2(p0, p1);
                }
                pfr[mt] = pk.s;
            }
            #pragma unroll
            for (int nt = 0; nt < 8; ++nt) {
                int cl = ng2 * 128 + nt * 16 + li;
                short8 vf = *(const short8*)&xb[cl * 256
                              + (((js * 4 + g) ^ (cl & 7)) << 3)];
                #pragma unroll
                for (int mt = 0; mt < 2; ++mt)
                    oacc[mt][nt] = __builtin_amdgcn_mfma_f32_16x16x32_bf16(
                        pfr[mt], vf, oacc[mt][nt], 0, 0, 0);
            }
        }

        size_t ob = (size_t)b * (256 * 256);
        #pragma unroll
        for (int mt = 0; mt < 2; ++mt)
            #pragma unroll
            for (int nt = 0; nt < 8; ++nt) {
                int c  = ng2 * 128 + nt * 16 + li;
                int i0 = ig2 * 32 + mt * 16 + 4 * g;
                #pragma unroll
                for (int q2 = 0; q2 < 4; ++q2)
                    out[ob + (size_t)(i0 + q2) * 256 + c] = oacc[mt][nt][q2];
            }
    }
}

extern "C" void kernel_launch(void* const* d_in, const int* in_sizes, int n_in,
                              void* d_out, int out_size, void* d_ws, size_t ws_size,
                              hipStream_t stream) {
    (void)in_sizes; (void)n_in; (void)out_size; (void)ws_size;
    const int*   seq   = (const int*)d_in[0];
    const float* emb   = (const float*)d_in[1];
    const float* pos   = (const float*)d_in[2];
    const float* W     = (const float*)d_in[3];
    const float* a1    = (const float*)d_in[4];
    const float* a2    = (const float*)d_in[5];
    const float* gamma = (const float*)d_in[6];
    const float* beta  = (const float*)d_in[7];

    char* ws = (char*)d_ws;
    u16*   wfrag = (u16*)ws;                     // 131072 B
    float* w1    = (float*)(ws + 131072);        // 1 KB
    float* w2    = (float*)(ws + 132096);        // 1 KB

    hipLaunchKernelGGL(prep, dim3(68), dim3(256), 0, stream, W, a1, a2, wfrag, w1, w2);
    hipLaunchKernelGGL(gat, dim3(256), dim3(1024), 0, stream,
                       seq, emb, pos, gamma, beta, w1, w2, wfrag, (float*)d_out);
}